// Round 3
// baseline (284.812 us; speedup 1.0000x reference)
//
#include <hip/hip_runtime.h>
#include <math.h>

// Problem constants (fixed by setup_inputs)
#define BB   32
#define CC   256
#define LL   4096
#define SS   8
#define CS   32
#define NT   256                 // threads per block (4 waves)
#define NW   (NT / 64)           // 4 waves
#define F4_ROW (LL / 4)          // 1024 float4 per row
#define F4_THR (F4_ROW / NT)     // 4 float4 per thread
#define NSEG  (NW * F4_THR)      // 16 64-float4 segments per row

__device__ __forceinline__ float gelu_exact(float x) {
    return 0.5f * x * (1.0f + erff(x * 0.70710678118654752440f));
}

// Barrier that orders LDS only: does NOT drain vmcnt, so in-flight global
// prefetch loads and output stores sail through. All cross-wave traffic in
// this kernel goes through LDS, so this is sufficient.
__device__ __forceinline__ void bar_lds() {
    asm volatile("s_waitcnt lgkmcnt(0)\n\ts_barrier" ::: "memory");
}

__global__ __launch_bounds__(NT, 4)
void hdconv_encoder_kernel(const float* __restrict__ inp,
                           const float* __restrict__ conv_w,   // [S,3,CS]
                           const float* __restrict__ conv_b,   // [S,CS]
                           const float* __restrict__ ln_g,     // [L]
                           const float* __restrict__ ln_b,     // [L]
                           const float* __restrict__ pw_w,     // [C]
                           const float* __restrict__ pw_b,     // [C]
                           float* __restrict__ out) {
    // Seam arrays: one float per 64-float4 segment (+1 sentinel each side).
    // Segment j = 4*k + wave covers float4 indices [64j_eq ...]; predecessor
    // of segment j is j-1 in this linear order (slices interleave waves).
    __shared__ float seamW[NSEG + 1];   // [1+j] = lane63's s.w of segment j; [0]=0
    __shared__ float seamX[NSEG + 1];   // [j]   = lane0's  s.x of segment j; [NSEG]=0
    __shared__ float red[2 * NW];       // per-wave {sum, sumsq}

    const int t    = threadIdx.x;
    const int blk  = blockIdx.x;      // [0, B*CS)
    const int b    = blk >> 5;        // batch
    const int c    = blk & 31;        // channel within group (block-uniform)
    const int lane = t & 63;
    const int wave = t >> 6;

    if (t == 0) { seamW[0] = 0.0f; seamX[NSEG] = 0.0f; }  // sentinels (never rewritten)

    // y_{i-1} for this thread's 16 positions (0 before group 0)
    float y[16];
#pragma unroll
    for (int j = 0; j < 16; ++j) y[j] = 0.0f;

    // gamma/beta cached in registers for the whole block (position-indexed)
    float4 g4[F4_THR], e4[F4_THR];
    {
        const float4* gp = (const float4*)ln_g;
        const float4* ep = (const float4*)ln_b;
#pragma unroll
        for (int k = 0; k < F4_THR; ++k) {
            g4[k] = gp[t + NT * k];
            e4[k] = ep[t + NT * k];
        }
    }

    // preload group 0's x row
    float4 xc[F4_THR];
    {
        const float4* xrow = (const float4*)(inp + ((size_t)(b * CC + c)) * LL);
#pragma unroll
        for (int k = 0; k < F4_THR; ++k) xc[k] = xrow[t + NT * k];
    }

    for (int i = 0; i < SS; ++i) {
        const int ch = i * CS + c;                        // global channel
        float4* orow = (float4*)(out + ((size_t)(b * CC + ch)) * LL);

        // ---- prefetch next group's x row (independent of everything below) ----
        const int inext = (i < SS - 1) ? (i + 1) : i;     // clamped (harmless reload)
        const float4* xnrow = (const float4*)(inp + ((size_t)(b * CC + inext * CS + c)) * LL);
        float4 xn[F4_THR];
#pragma unroll
        for (int k = 0; k < F4_THR; ++k) xn[k] = xnrow[t + NT * k];

        // ---- s = x_i + y_{i-1} in registers; publish seam scalars ----
        float4 s4[F4_THR];
#pragma unroll
        for (int k = 0; k < F4_THR; ++k) {
            s4[k].x = xc[k].x + y[4 * k + 0];
            s4[k].y = xc[k].y + y[4 * k + 1];
            s4[k].z = xc[k].z + y[4 * k + 2];
            s4[k].w = xc[k].w + y[4 * k + 3];
        }
        if (lane == 63) {
#pragma unroll
            for (int k = 0; k < F4_THR; ++k) seamW[1 + (k * NW + wave)] = s4[k].w;
        }
        if (lane == 0) {
#pragma unroll
            for (int k = 0; k < F4_THR; ++k) seamX[k * NW + wave] = s4[k].x;
        }
        bar_lds();   // (1) seams visible; does NOT wait for xn prefetch

        // block-uniform per-(group, c) params -> scalar loads
        const float w0 = conv_w[i * 96 + 0 * CS + c];
        const float w1 = conv_w[i * 96 + 1 * CS + c];
        const float w2 = conv_w[i * 96 + 2 * CS + c];
        const float bb = conv_b[i * CS + c];

        // ---- 3-tap depthwise conv from registers + shuffles + seams ----
        float lsum = 0.0f, lsq = 0.0f;
#pragma unroll
        for (int k = 0; k < F4_THR; ++k) {
            const int j = k * NW + wave;                  // segment id
            float sm1 = __shfl_up(s4[k].w, 1);            // s[4f-1] (lanes 1..63)
            float sp4 = __shfl_down(s4[k].x, 1);          // s[4f+4] (lanes 0..62)
            if (lane == 0)  sm1 = seamW[j];               // [0] sentinel = 0 at j=0
            if (lane == 63) sp4 = seamX[j + 1];           // [NSEG] sentinel = 0
            const float4 cc = s4[k];
            float y0 = fmaf(w0, sm1,  fmaf(w1, cc.x, fmaf(w2, cc.y, bb)));
            float y1 = fmaf(w0, cc.x, fmaf(w1, cc.y, fmaf(w2, cc.z, bb)));
            float y2 = fmaf(w0, cc.y, fmaf(w1, cc.z, fmaf(w2, cc.w, bb)));
            float y3 = fmaf(w0, cc.z, fmaf(w1, cc.w, fmaf(w2, sp4, bb)));
            y[4 * k + 0] = y0; y[4 * k + 1] = y1;
            y[4 * k + 2] = y2; y[4 * k + 3] = y3;
            lsum += (y0 + y1) + (y2 + y3);
            lsq  += fmaf(y0, y0, fmaf(y1, y1, fmaf(y2, y2, y3 * y3)));
        }

        // ---- LayerNorm stats: wave shuffle-reduce -> LDS -> broadcast fold ----
#pragma unroll
        for (int off = 32; off > 0; off >>= 1) {
            lsum += __shfl_down(lsum, off, 64);
            lsq  += __shfl_down(lsq,  off, 64);
        }
        if (lane == 0) { red[wave * 2] = lsum; red[wave * 2 + 1] = lsq; }
        bar_lds();   // (2) partials visible; also fences seam reuse next iter

        float sum = 0.0f, sq = 0.0f;
#pragma unroll
        for (int w = 0; w < NW; ++w) {
            sum += red[2 * w];
            sq  += red[2 * w + 1];
        }
        const float mean = sum * (1.0f / LL);
        const float var  = sq * (1.0f / LL) - mean * mean;
        const float inv  = rsqrtf(var + 1e-6f);

        // ---- normalize + pointwise + exact gelu + residual -> store ----
        const float pw = pw_w[ch];
        const float pb = pw_b[ch];
#pragma unroll
        for (int k = 0; k < F4_THR; ++k) {
            float4 o;
            float n;
            n   = fmaf((y[4 * k + 0] - mean) * inv, g4[k].x, e4[k].x);
            o.x = xc[k].x + gelu_exact(fmaf(n, pw, pb));
            n   = fmaf((y[4 * k + 1] - mean) * inv, g4[k].y, e4[k].y);
            o.y = xc[k].y + gelu_exact(fmaf(n, pw, pb));
            n   = fmaf((y[4 * k + 2] - mean) * inv, g4[k].z, e4[k].z);
            o.z = xc[k].z + gelu_exact(fmaf(n, pw, pb));
            n   = fmaf((y[4 * k + 3] - mean) * inv, g4[k].w, e4[k].w);
            o.w = xc[k].w + gelu_exact(fmaf(n, pw, pb));
            orow[t + NT * k] = o;   // store stays in flight; no barrier drains it
        }

        // rotate prefetched row in
#pragma unroll
        for (int k = 0; k < F4_THR; ++k) xc[k] = xn[k];
    }
}

extern "C" void kernel_launch(void* const* d_in, const int* in_sizes, int n_in,
                              void* d_out, int out_size, void* d_ws, size_t ws_size,
                              hipStream_t stream) {
    const float* inp    = (const float*)d_in[0];
    const float* conv_w = (const float*)d_in[1];
    const float* conv_b = (const float*)d_in[2];
    const float* ln_g   = (const float*)d_in[3];
    const float* ln_b   = (const float*)d_in[4];
    const float* pw_w   = (const float*)d_in[5];
    const float* pw_b   = (const float*)d_in[6];
    float* out = (float*)d_out;

    dim3 grid(BB * CS);   // 1024 blocks: one per (batch, within-group channel) chain
    dim3 block(NT);
    hdconv_encoder_kernel<<<grid, block, 0, stream>>>(
        inp, conv_w, conv_b, ln_g, ln_b, pw_w, pw_b, out);
}

// Round 4
// 266.838 us; speedup vs baseline: 1.0674x; 1.0674x over previous
//
#include <hip/hip_runtime.h>
#include <math.h>

// Problem constants
#define BBATCH 32
#define NCH    256
#define LLEN   4096
#define NGRP   8
#define CSZ    32
#define CORE   480            // core positions per wave-tile
#define HALO   16             // halo each side (need >=8 for 8-deep recurrence cone)
#define NTILE  9              // ceil(4096/480); tile 8 core = 256 positions
#define NCHAIN (BBATCH * CSZ) // 1024 independent (b,c) chains
#define NWAVE  (NCHAIN * NTILE)
#define NBLK   (NWAVE / 4)    // 2304 blocks of 4 waves

__device__ __forceinline__ float gelu_exact(float x) {
    return 0.5f * x * (1.0f + erff(x * 0.70710678118654752440f));
}

// Shared per-wave tile geometry. Each wave: lane l owns 8 positions starting
// at p0 = t*CORE - HALO + 8*l (ext range = 512 positions). Positions outside
// [0,L) are forced to s=0 (conv 'same' zero pad); wave-edge shuffle taps are
// garbage but contaminate <=8 positions inward, always inside the 16-halo.
struct TileGeom {
    int b, c, t, l;
    int p0, q0;         // logical start / clamped (aligned) load start
    bool force0;        // entire lane outside [0,L)
    bool coreval;       // lane's 8 positions are core (stored/summed)
};

__device__ __forceinline__ TileGeom tile_geom(int blockId, int tid) {
    TileGeom g;
    g.l = tid & 63;
    int wid = blockId * 4 + (tid >> 6);
    g.t = wid % NTILE;
    int chain = wid / NTILE;
    g.c = chain & 31;
    g.b = chain >> 5;
    g.p0 = g.t * CORE - HALO + 8 * g.l;
    int q = g.p0 < 0 ? 0 : g.p0;
    g.q0 = q > LLEN - 8 ? LLEN - 8 : q;
    g.force0 = (g.p0 < 0) || (g.p0 >= LLEN);
    const int coreLo = g.t * CORE;
    const int coreHi = (coreLo + CORE > LLEN) ? LLEN : (coreLo + CORE);
    g.coreval = (g.p0 >= coreLo) && (g.p0 < coreHi);
    return g;
}

// One recurrence step: given x (8 floats) and y_prev (8 floats), produce y.
// Taps via in-wave shuffles; force0 lanes contribute exact zero pads.
__device__ __forceinline__ void conv_step(const float* x, const float* yp, float* y,
                                          bool force0, float w0, float w1, float w2,
                                          float bc) {
    float s[8];
#pragma unroll
    for (int j = 0; j < 8; ++j) s[j] = force0 ? 0.0f : (x[j] + yp[j]);
    const float sL = __shfl_up(s[7], 1, 64);    // s[p0-1] from prev lane
    const float sR = __shfl_down(s[0], 1, 64);  // s[p0+8] from next lane
    y[0] = fmaf(w0, sL,   fmaf(w1, s[0], fmaf(w2, s[1], bc)));
#pragma unroll
    for (int j = 1; j < 7; ++j)
        y[j] = fmaf(w0, s[j - 1], fmaf(w1, s[j], fmaf(w2, s[j + 1], bc)));
    y[7] = fmaf(w0, s[6], fmaf(w1, s[7], fmaf(w2, sR, bc)));
}

// ---------------- K1: recurrence + LN partial sums (no LDS, no barriers) ----
__global__ __launch_bounds__(256, 6)
void k1_stats(const float* __restrict__ inp,
              const float* __restrict__ conv_w,   // [S,3,CS]
              const float* __restrict__ conv_b,   // [S,CS]
              float* __restrict__ stats) {        // [B,C,2] atomically accumulated
    const TileGeom g = tile_geom(blockIdx.x, threadIdx.x);

    float yp[8], y[8], x[8], aS[8], aQ[8];
#pragma unroll
    for (int j = 0; j < 8; ++j) yp[j] = 0.0f;

    const float4* rp0 = (const float4*)(inp + ((size_t)((g.b << 8) + g.c)) * LLEN) + (g.q0 >> 2);
    float4 xA = rp0[0], xB = rp0[1];

#pragma unroll
    for (int i = 0; i < NGRP; ++i) {
        float4 nA, nB;
        if (i < NGRP - 1) {   // prefetch next row (stays in flight over compute)
            const float4* np = (const float4*)(inp + ((size_t)((g.b << 8) + (i + 1) * CSZ + g.c)) * LLEN) + (g.q0 >> 2);
            nA = np[0]; nB = np[1];
        }
        x[0] = xA.x; x[1] = xA.y; x[2] = xA.z; x[3] = xA.w;
        x[4] = xB.x; x[5] = xB.y; x[6] = xB.z; x[7] = xB.w;

        const float w0 = conv_w[i * 96 + g.c];
        const float w1 = conv_w[i * 96 + 32 + g.c];
        const float w2 = conv_w[i * 96 + 64 + g.c];
        const float bc = conv_b[i * 32 + g.c];
        conv_step(x, yp, y, g.force0, w0, w1, w2, bc);

        float s1 = 0.0f, s2 = 0.0f;
#pragma unroll
        for (int j = 0; j < 8; ++j) { s1 += y[j]; s2 = fmaf(y[j], y[j], s2); }
        aS[i] = s1; aQ[i] = s2;
#pragma unroll
        for (int j = 0; j < 8; ++j) yp[j] = y[j];
        if (i < NGRP - 1) { xA = nA; xB = nB; }
    }

    // mask halo/OOB lanes, butterfly-reduce 16 values across the wave
    if (!g.coreval) {
#pragma unroll
        for (int i = 0; i < 8; ++i) { aS[i] = 0.0f; aQ[i] = 0.0f; }
    }
#pragma unroll
    for (int m = 1; m < 64; m <<= 1) {
#pragma unroll
        for (int i = 0; i < 8; ++i) {
            aS[i] += __shfl_xor(aS[i], m, 64);
            aQ[i] += __shfl_xor(aQ[i], m, 64);
        }
    }
    if (g.l == 0) {
#pragma unroll
        for (int i = 0; i < 8; ++i) {
            const int idx = (g.b << 8) + (i << 5) + g.c;
            atomicAdd(&stats[2 * idx],     aS[i]);
            atomicAdd(&stats[2 * idx + 1], aQ[i]);
        }
    }
}

// ---------------- K2: recompute recurrence + LN + gelu + residual -----------
__global__ __launch_bounds__(256, 4)
void k2_apply(const float* __restrict__ inp,
              const float* __restrict__ conv_w,
              const float* __restrict__ conv_b,
              const float* __restrict__ ln_g,
              const float* __restrict__ ln_b,
              const float* __restrict__ pw_w,
              const float* __restrict__ pw_b,
              const float* __restrict__ stats,
              float* __restrict__ out) {
    const TileGeom g = tile_geom(blockIdx.x, threadIdx.x);

    // gamma/beta for this lane's positions (shared across all 8 rows)
    const float4* gp = (const float4*)ln_g + (g.q0 >> 2);
    const float4* ep = (const float4*)ln_b + (g.q0 >> 2);
    const float4 gA = gp[0], gB = gp[1];
    const float4 eA = ep[0], eB = ep[1];
    float gam[8] = {gA.x, gA.y, gA.z, gA.w, gB.x, gB.y, gB.z, gB.w};
    float bet[8] = {eA.x, eA.y, eA.z, eA.w, eB.x, eB.y, eB.z, eB.w};

    float yp[8], y[8], x[8];
#pragma unroll
    for (int j = 0; j < 8; ++j) yp[j] = 0.0f;

    const float4* rp0 = (const float4*)(inp + ((size_t)((g.b << 8) + g.c)) * LLEN) + (g.q0 >> 2);
    float4 xA = rp0[0], xB = rp0[1];

#pragma unroll
    for (int i = 0; i < NGRP; ++i) {
        float4 nA, nB;
        if (i < NGRP - 1) {
            const float4* np = (const float4*)(inp + ((size_t)((g.b << 8) + (i + 1) * CSZ + g.c)) * LLEN) + (g.q0 >> 2);
            nA = np[0]; nB = np[1];
        }
        x[0] = xA.x; x[1] = xA.y; x[2] = xA.z; x[3] = xA.w;
        x[4] = xB.x; x[5] = xB.y; x[6] = xB.z; x[7] = xB.w;

        const int ch = (i << 5) + g.c;
        const float w0 = conv_w[i * 96 + g.c];
        const float w1 = conv_w[i * 96 + 32 + g.c];
        const float w2 = conv_w[i * 96 + 64 + g.c];
        const float bc = conv_b[i * 32 + g.c];
        conv_step(x, yp, y, g.force0, w0, w1, w2, bc);

        // finalized LN stats for this (b, ch) row (written by K1)
        const int idx = (g.b << 8) + ch;
        const float S = stats[2 * idx];
        const float Q = stats[2 * idx + 1];
        const float mean = S * (1.0f / LLEN);
        const float var  = fmaf(-mean, mean, Q * (1.0f / LLEN));
        const float inv  = rsqrtf(var + 1e-6f);
        const float pwv  = pw_w[ch];
        const float pbv  = pw_b[ch];

        if (g.coreval) {
            float o[8];
#pragma unroll
            for (int j = 0; j < 8; ++j) {
                const float n = fmaf((y[j] - mean) * inv, gam[j], bet[j]);
                o[j] = x[j] + gelu_exact(fmaf(n, pwv, pbv));
            }
            float4* op = (float4*)(out + ((size_t)((g.b << 8) + ch)) * LLEN) + (g.q0 >> 2);
            op[0] = make_float4(o[0], o[1], o[2], o[3]);
            op[1] = make_float4(o[4], o[5], o[6], o[7]);
        }

#pragma unroll
        for (int j = 0; j < 8; ++j) yp[j] = y[j];
        if (i < NGRP - 1) { xA = nA; xB = nB; }
    }
}

extern "C" void kernel_launch(void* const* d_in, const int* in_sizes, int n_in,
                              void* d_out, int out_size, void* d_ws, size_t ws_size,
                              hipStream_t stream) {
    const float* inp    = (const float*)d_in[0];
    const float* conv_w = (const float*)d_in[1];
    const float* conv_b = (const float*)d_in[2];
    const float* ln_g   = (const float*)d_in[3];
    const float* ln_b   = (const float*)d_in[4];
    const float* pw_w   = (const float*)d_in[5];
    const float* pw_b   = (const float*)d_in[6];
    float* out   = (float*)d_out;
    float* stats = (float*)d_ws;                       // [32,256,2] fp32 accumulators

    hipMemsetAsync(d_ws, 0, BBATCH * NCH * 2 * sizeof(float), stream);
    k1_stats<<<NBLK, 256, 0, stream>>>(inp, conv_w, conv_b, stats);
    k2_apply<<<NBLK, 256, 0, stream>>>(inp, conv_w, conv_b, ln_g, ln_b,
                                       pw_w, pw_b, stats, out);
}